// Round 3
// baseline (2314.364 us; speedup 1.0000x reference)
//
#include <hip/hip_runtime.h>
#include <hip/hip_bf16.h>
#include <math.h>

// 3-layer GCN on MI355X.
// R6 (resubmit — prior round died on GPU acquisition, never ran):
//   Bucket-partition redesign — NO per-node returning atomics anywhere.
//   Nodes grouped in buckets of 128 (NB=ceil(N/128)). Build = 2-pass edge
//   partition by bucket with LDS-privatized histograms (782 bins) and packed
//   edges (row<<7 | col_local, 24 bits). Agg = block per bucket: fp32
//   accumulators for 128 nodes x 64 feats live in LDS (feat-major, stride
//   129 for bank spread), init = self-loop, edges streamed coalesced,
//   gather 16B/lane (8 lanes per edge), ds_add_f32 accumulate.
//   Degree rebuilt from part[] via LDS int histograms. No cap / slow path.

#define FDIM 64
#define BKT 128              // nodes per bucket
#define MAXNB 1024           // max buckets supported (N <= 131072)

// ---------- build: bucket partition ----------

__global__ __launch_bounds__(256) void partA_kernel(const int* __restrict__ ecol,
                                                    int* __restrict__ gcnt,
                                                    int e, int nb, int epb) {
    __shared__ int lh[MAXNB];
    const int t = threadIdx.x;
    for (int i = t; i < nb; i += 256) lh[i] = 0;
    __syncthreads();
    int s = blockIdx.x * epb;
    int en = s + epb; if (en > e) en = e;
    for (int i = s + t; i < en; i += 256) atomicAdd(&lh[ecol[i] >> 7], 1);
    __syncthreads();
    for (int i = t; i < nb; i += 256)
        if (lh[i]) atomicAdd(&gcnt[i], lh[i]);
}

__global__ __launch_bounds__(1024) void scan_kernel(const int* __restrict__ gcnt,
                                                    int* __restrict__ base,
                                                    int* __restrict__ cursor, int nb) {
    __shared__ int s[1024];
    const int t = threadIdx.x;
    int v = (t < nb) ? gcnt[t] : 0;
    s[t] = v;
    __syncthreads();
    for (int off = 1; off < 1024; off <<= 1) {
        int x = (t >= off) ? s[t - off] : 0;
        __syncthreads();
        s[t] += x;
        __syncthreads();
    }
    int incl = s[t];
    if (t < nb) { base[t] = incl - v; cursor[t] = incl - v; }
    if (t == nb - 1) base[nb] = incl;
}

__global__ __launch_bounds__(256) void partB_kernel(const int* __restrict__ erow,
                                                    const int* __restrict__ ecol,
                                                    int* __restrict__ cursor,
                                                    unsigned* __restrict__ part,
                                                    int e, int nb, int epb) {
    __shared__ int lh[MAXNB];
    __shared__ int lbase[MAXNB];
    const int t = threadIdx.x;
    for (int i = t; i < nb; i += 256) lh[i] = 0;
    __syncthreads();
    int s = blockIdx.x * epb;
    int en = s + epb; if (en > e) en = e;
    for (int i = s + t; i < en; i += 256) atomicAdd(&lh[ecol[i] >> 7], 1);
    __syncthreads();
    for (int i = t; i < nb; i += 256)
        lbase[i] = lh[i] ? atomicAdd(&cursor[i], lh[i]) : 0;
    __syncthreads();
    for (int i = t; i < nb; i += 256) lh[i] = 0;
    __syncthreads();
    for (int i = s + t; i < en; i += 256) {
        int c = ecol[i];
        int b = c >> 7;
        int off = atomicAdd(&lh[b], 1);
        part[lbase[b] + off] = ((unsigned)erow[i] << 7) | (unsigned)(c & 127);
    }
}

// per-node in-degree from partitioned edges (LDS histogram per bucket)
__global__ __launch_bounds__(256) void cnt_kernel(const unsigned* __restrict__ part,
                                                  const int* __restrict__ base,
                                                  int* __restrict__ cnt, int n) {
    const int b = blockIdx.x;
    const int v0 = b << 7;
    __shared__ int lc[BKT];
    const int t = threadIdx.x;
    if (t < BKT) lc[t] = 0;
    __syncthreads();
    const int s0 = base[b], s1 = base[b + 1];
    for (int e = s0 + t; e < s1; e += 256) atomicAdd(&lc[part[e] & 127], 1);
    __syncthreads();
    int nn = n - v0; if (nn > BKT) nn = BKT;
    if (t < nn) cnt[v0 + t] = lc[t];
}

// ---------- per-layer compute ----------

// Hs[n,64] = bf16( rsqrt(cnt+1) * (X[n,64] @ W[64,64]) )
__global__ __launch_bounds__(256) void gemm_kernel(const float* __restrict__ X,
                                                   const float* __restrict__ W,
                                                   const int* __restrict__ cnt,
                                                   __hip_bfloat16* __restrict__ Hout, int n) {
    __shared__ float Ws[64][64];
    __shared__ float Xs[64][64];
    const int t = threadIdx.x;
    const int row0 = blockIdx.x * 64;
    #pragma unroll
    for (int i = t; i < 4096; i += 256) Ws[i >> 6][i & 63] = W[i];
    #pragma unroll
    for (int i = t; i < 4096; i += 256) {
        int r = i >> 6, c = i & 63;
        int gr = row0 + r;
        Xs[r][c] = (gr < n) ? X[(size_t)gr * FDIM + c] : 0.0f;
    }
    __syncthreads();
    const int j = t & 63;
    const int ng = t >> 6;
    float acc[16];
    #pragma unroll
    for (int r = 0; r < 16; r++) acc[r] = 0.0f;
    for (int k = 0; k < 64; k++) {
        float w = Ws[k][j];
        #pragma unroll
        for (int r = 0; r < 16; r++)
            acc[r] += Xs[ng * 16 + r][k] * w;
    }
    #pragma unroll
    for (int r = 0; r < 16; r++) {
        int gr = row0 + ng * 16 + r;
        if (gr < n) {
            float dv = rsqrtf((float)cnt[gr] + 1.0f);   // +1 self loop
            Hout[(size_t)gr * FDIM + j] = __float2bfloat16(acc[r] * dv);
        }
    }
}

__device__ inline void unpack8(uint4 w, float* f) {
    f[0] = __uint_as_float(w.x << 16);
    f[1] = __uint_as_float(w.x & 0xffff0000u);
    f[2] = __uint_as_float(w.y << 16);
    f[3] = __uint_as_float(w.y & 0xffff0000u);
    f[4] = __uint_as_float(w.z << 16);
    f[5] = __uint_as_float(w.z & 0xffff0000u);
    f[6] = __uint_as_float(w.w << 16);
    f[7] = __uint_as_float(w.w & 0xffff0000u);
}

// Block per bucket: LDS fp32 accumulators [feat][node_local] (stride 129),
// init = hs[v] (self loop), stream edges: 8 lanes/edge, 16B gather each,
// ds_add_f32 accumulate. Epilogue: *dinv + bias (+ELU), coalesced.
__global__ __launch_bounds__(256) void agg_kernel(const __hip_bfloat16* __restrict__ hs,
                                                  const unsigned* __restrict__ part,
                                                  const int* __restrict__ base,
                                                  const int* __restrict__ cnt,
                                                  const float* __restrict__ bias,
                                                  float* __restrict__ out,
                                                  int n, int do_elu) {
    const int b = blockIdx.x;
    const int v0 = b << 7;
    int nn = n - v0; if (nn > BKT) nn = BKT;
    __shared__ float acc[64 * 129];          // acc[f*129 + c], 33 KB
    const int t = threadIdx.x;
    const uint4* __restrict__ hs4 = (const uint4*)hs;

    // init with self-loop values: acc[f][c] = f32(hs[v0+c][f])
    for (int i = t; i < nn * 8; i += 256) {
        int c = i >> 3, k = i & 7;
        uint4 w = hs4[(size_t)(v0 + c) * 8 + k];
        float f[8];
        unpack8(w, f);
        #pragma unroll
        for (int j = 0; j < 8; j++) acc[(k * 8 + j) * 129 + c] = f[j];
    }
    __syncthreads();

    const int estart = base[b], eend = base[b + 1];
    const int fb = t & 7;                    // feature block (8 feats, 16B)
    const int es = t >> 3;                   // edge slot 0..31
    for (int e0 = estart; e0 < eend; e0 += 64) {
        int eA = e0 + es;
        int eB = e0 + 32 + es;
        unsigned pkA = 0, pkB = 0;
        bool va = eA < eend, vb = eB < eend;
        if (va) pkA = part[eA];
        if (vb) pkB = part[eB];
        uint4 wA, wB;
        if (va) wA = hs4[(size_t)(pkA >> 7) * 8 + fb];
        if (vb) wB = hs4[(size_t)(pkB >> 7) * 8 + fb];
        if (va) {
            float f[8];
            unpack8(wA, f);
            int c = pkA & 127;
            #pragma unroll
            for (int j = 0; j < 8; j++) atomicAdd(&acc[(fb * 8 + j) * 129 + c], f[j]);
        }
        if (vb) {
            float f[8];
            unpack8(wB, f);
            int c = pkB & 127;
            #pragma unroll
            for (int j = 0; j < 8; j++) atomicAdd(&acc[(fb * 8 + j) * 129 + c], f[j]);
        }
    }
    __syncthreads();

    // epilogue: out[v][f] = acc[f][c] * dinv(v) + bias[f] (+ ELU)
    for (int i = t; i < nn * 64; i += 256) {
        int c = i >> 6, f = i & 63;
        float s = acc[f * 129 + c];
        float dv = rsqrtf((float)cnt[v0 + c] + 1.0f);
        float r = s * dv + bias[f];
        if (do_elu) r = (r > 0.0f) ? r : (__expf(r) - 1.0f);
        out[(size_t)(v0 + c) * FDIM + f] = r;
    }
}

// ---------- launch ----------

extern "C" void kernel_launch(void* const* d_in, const int* in_sizes, int n_in,
                              void* d_out, int out_size, void* d_ws, size_t ws_size,
                              hipStream_t stream) {
    const float* x   = (const float*)d_in[0];
    const int*   ei  = (const int*)d_in[1];
    const float* W1  = (const float*)d_in[2];
    const float* b1  = (const float*)d_in[3];
    const float* W2  = (const float*)d_in[4];
    const float* b2  = (const float*)d_in[5];
    const float* W3  = (const float*)d_in[6];
    const float* b3  = (const float*)d_in[7];

    const int N = in_sizes[0] / FDIM;      // 100000
    const int E = in_sizes[1] / 2;         // 1600000
    const int* erow = ei;                   // sources
    const int* ecol = ei + E;               // targets

    const int NB = (N + BKT - 1) / BKT;    // 782 buckets

    char* p = (char*)d_ws;
    __hip_bfloat16* hsb = (__hip_bfloat16*)p;  p += (size_t)N * FDIM * sizeof(__hip_bfloat16); // 12.8 MB
    int*      cnt  = (int*)p;      p += (size_t)N * sizeof(int);
    unsigned* part = (unsigned*)p; p += (size_t)E * sizeof(unsigned);                          // 6.4 MB
    int* gcnt   = (int*)p; p += (size_t)(NB + 1) * sizeof(int);
    int* bbase  = (int*)p; p += (size_t)(NB + 1) * sizeof(int);
    int* cursor = (int*)p; p += (size_t)(NB + 1) * sizeof(int);

    float* outb = (float*)d_out;

    const int TB = 256;
    const int PBLK = 256;                        // partition blocks
    const int epb = (E + PBLK - 1) / PBLK;       // edges per partition block
    const int nblkG = (N + 63) / 64;

    hipMemsetAsync(gcnt, 0, (size_t)(NB + 1) * sizeof(int), stream);
    partA_kernel<<<PBLK, TB, 0, stream>>>(ecol, gcnt, E, NB, epb);
    scan_kernel<<<1, 1024, 0, stream>>>(gcnt, bbase, cursor, NB);
    partB_kernel<<<PBLK, TB, 0, stream>>>(erow, ecol, cursor, part, E, NB, epb);
    cnt_kernel<<<NB, TB, 0, stream>>>(part, bbase, cnt, N);

    gemm_kernel<<<nblkG, TB, 0, stream>>>(x, W1, cnt, hsb, N);
    agg_kernel<<<NB, TB, 0, stream>>>(hsb, part, bbase, cnt, b1, outb, N, 1);
    gemm_kernel<<<nblkG, TB, 0, stream>>>(outb, W2, cnt, hsb, N);
    agg_kernel<<<NB, TB, 0, stream>>>(hsb, part, bbase, cnt, b2, outb, N, 1);
    gemm_kernel<<<nblkG, TB, 0, stream>>>(outb, W3, cnt, hsb, N);
    agg_kernel<<<NB, TB, 0, stream>>>(hsb, part, bbase, cnt, b3, outb, N, 0);
}

// Round 4
// 431.385 us; speedup vs baseline: 5.3650x; 5.3650x over previous
//
#include <hip/hip_runtime.h>
#include <hip/hip_bf16.h>
#include <math.h>

// 3-layer GCN on MI355X.
// R7: hybrid — R6's bucket partition (correct, no per-node global atomics)
//     feeds a per-bucket adjw_kernel that builds R4's fixed-stride adjacency
//     via LDS *int* counters (native ds_add_rtn_u32; R6's fp32 LDS atomics
//     were CAS loops -> 689us agg). Agg reverts to R4's proven wave-per-node
//     register-accumulation kernel. part[] aliases hsb (dead until gemm1).

#define FDIM 64
#define BKT 128              // nodes per bucket
#define MAXNB 1024           // max buckets supported (N <= 131072)

// ---------- build: bucket partition ----------

__global__ __launch_bounds__(256) void partA_kernel(const int* __restrict__ ecol,
                                                    int* __restrict__ gcnt,
                                                    int e, int nb, int epb) {
    __shared__ int lh[MAXNB];
    const int t = threadIdx.x;
    for (int i = t; i < nb; i += 256) lh[i] = 0;
    __syncthreads();
    int s = blockIdx.x * epb;
    int en = s + epb; if (en > e) en = e;
    for (int i = s + t; i < en; i += 256) atomicAdd(&lh[ecol[i] >> 7], 1);
    __syncthreads();
    for (int i = t; i < nb; i += 256)
        if (lh[i]) atomicAdd(&gcnt[i], lh[i]);
}

__global__ __launch_bounds__(1024) void scan_kernel(const int* __restrict__ gcnt,
                                                    int* __restrict__ base,
                                                    int* __restrict__ cursor, int nb) {
    __shared__ int s[1024];
    const int t = threadIdx.x;
    int v = (t < nb) ? gcnt[t] : 0;
    s[t] = v;
    __syncthreads();
    for (int off = 1; off < 1024; off <<= 1) {
        int x = (t >= off) ? s[t - off] : 0;
        __syncthreads();
        s[t] += x;
        __syncthreads();
    }
    int incl = s[t];
    if (t < nb) { base[t] = incl - v; cursor[t] = incl - v; }
    if (t == nb - 1) base[nb] = incl;
}

__global__ __launch_bounds__(256) void partB_kernel(const int* __restrict__ erow,
                                                    const int* __restrict__ ecol,
                                                    int* __restrict__ cursor,
                                                    unsigned* __restrict__ part,
                                                    int e, int nb, int epb) {
    __shared__ int lh[MAXNB];
    __shared__ int lbase[MAXNB];
    const int t = threadIdx.x;
    for (int i = t; i < nb; i += 256) lh[i] = 0;
    __syncthreads();
    int s = blockIdx.x * epb;
    int en = s + epb; if (en > e) en = e;
    for (int i = s + t; i < en; i += 256) atomicAdd(&lh[ecol[i] >> 7], 1);
    __syncthreads();
    for (int i = t; i < nb; i += 256)
        lbase[i] = lh[i] ? atomicAdd(&cursor[i], lh[i]) : 0;
    __syncthreads();
    for (int i = t; i < nb; i += 256) lh[i] = 0;
    __syncthreads();
    for (int i = s + t; i < en; i += 256) {
        int c = ecol[i];
        int b = c >> 7;
        int off = atomicAdd(&lh[b], 1);
        part[lbase[b] + off] = ((unsigned)erow[i] << 7) | (unsigned)(c & 127);
    }
}

// per-bucket: partitioned edges -> fixed-stride adjacency + per-node degree.
// LDS int counters only (native ds_add_rtn_u32).
__global__ __launch_bounds__(256) void adjw_kernel(const unsigned* __restrict__ part,
                                                   const int* __restrict__ base,
                                                   int* __restrict__ cnt,
                                                   int* __restrict__ adjF,
                                                   int n, int cap) {
    const int b = blockIdx.x;
    const int v0 = b << 7;
    __shared__ int lc[BKT];
    const int t = threadIdx.x;
    if (t < BKT) lc[t] = 0;
    __syncthreads();
    const int s0 = base[b], s1 = base[b + 1];
    for (int e = s0 + t; e < s1; e += 256) {
        unsigned pk = part[e];
        int c = pk & 127;
        int slot = atomicAdd(&lc[c], 1);
        if (slot < cap) adjF[(size_t)(v0 + c) * cap + slot] = (int)(pk >> 7);
    }
    __syncthreads();
    int nn = n - v0; if (nn > BKT) nn = BKT;
    if (t < nn) cnt[v0 + t] = lc[t];
}

// ---------- per-layer compute ----------

// Hs[n,64] = bf16( rsqrt(cnt+1) * (X[n,64] @ W[64,64]) )
__global__ __launch_bounds__(256) void gemm_kernel(const float* __restrict__ X,
                                                   const float* __restrict__ W,
                                                   const int* __restrict__ cnt,
                                                   __hip_bfloat16* __restrict__ Hout, int n) {
    __shared__ float Ws[64][64];
    __shared__ float Xs[64][64];
    const int t = threadIdx.x;
    const int row0 = blockIdx.x * 64;
    #pragma unroll
    for (int i = t; i < 4096; i += 256) Ws[i >> 6][i & 63] = W[i];
    #pragma unroll
    for (int i = t; i < 4096; i += 256) {
        int r = i >> 6, c = i & 63;
        int gr = row0 + r;
        Xs[r][c] = (gr < n) ? X[(size_t)gr * FDIM + c] : 0.0f;
    }
    __syncthreads();
    const int j = t & 63;
    const int ng = t >> 6;
    float acc[16];
    #pragma unroll
    for (int r = 0; r < 16; r++) acc[r] = 0.0f;
    for (int k = 0; k < 64; k++) {
        float w = Ws[k][j];
        #pragma unroll
        for (int r = 0; r < 16; r++)
            acc[r] += Xs[ng * 16 + r][k] * w;
    }
    #pragma unroll
    for (int r = 0; r < 16; r++) {
        int gr = row0 + ng * 16 + r;
        if (gr < n) {
            float dv = rsqrtf((float)cnt[gr] + 1.0f);   // +1 self loop
            Hout[(size_t)gr * FDIM + j] = __float2bfloat16(acc[r] * dv);
        }
    }
}

// out[v][:] = dinv(v) * ( hs[v][:] + sum_{u in N_in(v)} hs[u][:] ) + b ; optional ELU.
// Wave per node. lane&31 = feature PAIR (bf16x2); lane>>5 = half (even/odd edges).
// Register accumulation (R4-proven).
__global__ __launch_bounds__(256) void agg_kernel(const __hip_bfloat16* __restrict__ hs,
                                                  const int* __restrict__ adjF,
                                                  const int* __restrict__ cnt,
                                                  const float* __restrict__ bias,
                                                  float* __restrict__ out,
                                                  int n, int cap, int do_elu,
                                                  const int* __restrict__ erow,
                                                  const int* __restrict__ ecol, int etot) {
    const int v = blockIdx.x * 4 + (threadIdx.x >> 6);
    const int lane = threadIdx.x & 63;
    if (v >= n) return;
    const int f2 = lane & 31;
    const int half = lane >> 5;
    const int deg = cnt[v];
    const float dv = rsqrtf((float)deg + 1.0f);         // +1 self loop
    const __hip_bfloat162* __restrict__ hs2 = (const __hip_bfloat162*)hs;

    float2 a0 = {0.f,0.f}, a1 = {0.f,0.f}, a2 = {0.f,0.f}, a3 = {0.f,0.f};
    float2 a4 = {0.f,0.f}, a5 = {0.f,0.f}, a6 = {0.f,0.f}, a7 = {0.f,0.f};

    // self loop (add once: half 0 only)
    if (half == 0) {
        __hip_bfloat162 sv = hs2[(size_t)v * 32 + f2];
        a0.x = __bfloat162float(sv.x);
        a0.y = __bfloat162float(sv.y);
    }

    if (deg <= cap) {                       // fast path (always, in practice)
        const int* __restrict__ av = adjF + (size_t)v * cap;
        for (int base = 0; base < deg; base += 64) {
            int m = deg - base; if (m > 64) m = 64;
            int uvec = 0;
            if (lane < m) uvec = av[base + lane];        // coalesced
            const int pairs = m >> 1;
            int k = 0;
            for (; k + 8 <= pairs; k += 8) {
                int u0 = __shfl(uvec, 2*(k+0) + half, 64);
                int u1 = __shfl(uvec, 2*(k+1) + half, 64);
                int u2 = __shfl(uvec, 2*(k+2) + half, 64);
                int u3 = __shfl(uvec, 2*(k+3) + half, 64);
                int u4 = __shfl(uvec, 2*(k+4) + half, 64);
                int u5 = __shfl(uvec, 2*(k+5) + half, 64);
                int u6 = __shfl(uvec, 2*(k+6) + half, 64);
                int u7 = __shfl(uvec, 2*(k+7) + half, 64);
                __hip_bfloat162 b0 = hs2[(size_t)u0 * 32 + f2];
                __hip_bfloat162 b1 = hs2[(size_t)u1 * 32 + f2];
                __hip_bfloat162 b2 = hs2[(size_t)u2 * 32 + f2];
                __hip_bfloat162 b3 = hs2[(size_t)u3 * 32 + f2];
                __hip_bfloat162 b4 = hs2[(size_t)u4 * 32 + f2];
                __hip_bfloat162 b5 = hs2[(size_t)u5 * 32 + f2];
                __hip_bfloat162 b6 = hs2[(size_t)u6 * 32 + f2];
                __hip_bfloat162 b7 = hs2[(size_t)u7 * 32 + f2];
                a0.x += __bfloat162float(b0.x); a0.y += __bfloat162float(b0.y);
                a1.x += __bfloat162float(b1.x); a1.y += __bfloat162float(b1.y);
                a2.x += __bfloat162float(b2.x); a2.y += __bfloat162float(b2.y);
                a3.x += __bfloat162float(b3.x); a3.y += __bfloat162float(b3.y);
                a4.x += __bfloat162float(b4.x); a4.y += __bfloat162float(b4.y);
                a5.x += __bfloat162float(b5.x); a5.y += __bfloat162float(b5.y);
                a6.x += __bfloat162float(b6.x); a6.y += __bfloat162float(b6.y);
                a7.x += __bfloat162float(b7.x); a7.y += __bfloat162float(b7.y);
            }
            for (; k < pairs; k++) {
                int u = __shfl(uvec, 2*k + half, 64);
                __hip_bfloat162 b = hs2[(size_t)u * 32 + f2];
                a0.x += __bfloat162float(b.x); a0.y += __bfloat162float(b.y);
            }
            if (m & 1) {                                  // odd tail edge
                int u = __shfl(uvec, m - 1, 64);
                if (half == 0) {
                    __hip_bfloat162 b = hs2[(size_t)u * 32 + f2];
                    a1.x += __bfloat162float(b.x); a1.y += __bfloat162float(b.y);
                }
            }
        }
    } else {
        // slow path: deg > cap (prob ~0) — wave-cooperative scan of raw edges
        for (int base = 0; base < etot; base += 64) {
            int m = etot - base; if (m > 64) m = 64;
            int c = -1, r = 0;
            if (lane < m) { c = ecol[base + lane]; r = erow[base + lane]; }
            unsigned long long mask = __ballot(c == v);
            while (mask) {
                int j = __ffsll((long long)mask) - 1;
                mask &= mask - 1;
                int u = __shfl(r, j, 64);
                if (half == 0) {
                    __hip_bfloat162 b = hs2[(size_t)u * 32 + f2];
                    a0.x += __bfloat162float(b.x); a0.y += __bfloat162float(b.y);
                }
            }
        }
    }

    float2 tot;
    tot.x = ((a0.x + a1.x) + (a2.x + a3.x)) + ((a4.x + a5.x) + (a6.x + a7.x));
    tot.y = ((a0.y + a1.y) + (a2.y + a3.y)) + ((a4.y + a5.y) + (a6.y + a7.y));
    tot.x += __shfl_xor(tot.x, 32, 64);    // combine halves
    tot.y += __shfl_xor(tot.y, 32, 64);

    if (half == 0) {
        float2 bv = ((const float2*)bias)[f2];
        float rx = tot.x * dv + bv.x;
        float ry = tot.y * dv + bv.y;
        if (do_elu) {
            rx = (rx > 0.0f) ? rx : (__expf(rx) - 1.0f);
            ry = (ry > 0.0f) ? ry : (__expf(ry) - 1.0f);
        }
        ((float2*)out)[(size_t)v * 32 + f2] = make_float2(rx, ry);
    }
}

// ---------- launch ----------

extern "C" void kernel_launch(void* const* d_in, const int* in_sizes, int n_in,
                              void* d_out, int out_size, void* d_ws, size_t ws_size,
                              hipStream_t stream) {
    const float* x   = (const float*)d_in[0];
    const int*   ei  = (const int*)d_in[1];
    const float* W1  = (const float*)d_in[2];
    const float* b1  = (const float*)d_in[3];
    const float* W2  = (const float*)d_in[4];
    const float* b2  = (const float*)d_in[5];
    const float* W3  = (const float*)d_in[6];
    const float* b3  = (const float*)d_in[7];

    const int N = in_sizes[0] / FDIM;      // 100000
    const int E = in_sizes[1] / 2;         // 1600000
    const int* erow = ei;                   // sources
    const int* ecol = ei + E;               // targets

    const int NB = (N + BKT - 1) / BKT;    // 782 buckets

    char* p = (char*)d_ws;
    __hip_bfloat16* hsb = (__hip_bfloat16*)p;  p += (size_t)N * FDIM * sizeof(__hip_bfloat16); // 12.8 MB
    int*   cnt  = (int*)p;   p += (size_t)N * sizeof(int);
    int* gcnt   = (int*)p;   p += (size_t)(NB + 1) * sizeof(int);
    int* bbase  = (int*)p;   p += (size_t)(NB + 1) * sizeof(int);
    int* cursor = (int*)p;   p += (size_t)(NB + 1) * sizeof(int);
    int*   adjF = (int*)p;

    // part[] aliases hsb: E*4 = 6.4MB <= N*128B = 12.8MB; dead before gemm1 writes hsb.
    unsigned* part = (unsigned*)hsb;

    // adjacency capacity: biggest of {64,48,32} that fits the workspace
    size_t used = (size_t)(p - (char*)d_ws);
    int cap = 64;
    while (cap > 32 && used + (size_t)N * cap * sizeof(int) > ws_size) cap -= 16;

    float* outb = (float*)d_out;

    const int TB = 256;
    const int PBLK = 256;                        // partition blocks
    const int epb = (E + PBLK - 1) / PBLK;       // edges per partition block
    const int nblkG = (N + 63) / 64;
    const int nblkA = (N + 3) / 4;

    hipMemsetAsync(gcnt, 0, (size_t)(NB + 1) * sizeof(int), stream);
    partA_kernel<<<PBLK, TB, 0, stream>>>(ecol, gcnt, E, NB, epb);
    scan_kernel<<<1, 1024, 0, stream>>>(gcnt, bbase, cursor, NB);
    partB_kernel<<<PBLK, TB, 0, stream>>>(erow, ecol, cursor, part, E, NB, epb);
    adjw_kernel<<<NB, TB, 0, stream>>>(part, bbase, cnt, adjF, N, cap);

    gemm_kernel<<<nblkG, TB, 0, stream>>>(x, W1, cnt, hsb, N);
    agg_kernel<<<nblkA, TB, 0, stream>>>(hsb, adjF, cnt, b1, outb, N, cap, 1, erow, ecol, E);
    gemm_kernel<<<nblkG, TB, 0, stream>>>(outb, W2, cnt, hsb, N);
    agg_kernel<<<nblkA, TB, 0, stream>>>(hsb, adjF, cnt, b2, outb, N, cap, 1, erow, ecol, E);
    gemm_kernel<<<nblkG, TB, 0, stream>>>(outb, W3, cnt, hsb, N);
    agg_kernel<<<nblkA, TB, 0, stream>>>(hsb, adjF, cnt, b3, outb, N, cap, 0, erow, ecol, E);
}

// Round 5
// 356.246 us; speedup vs baseline: 6.4965x; 1.2109x over previous
//
#include <hip/hip_runtime.h>
#include <hip/hip_bf16.h>
#include <math.h>

// 3-layer GCN on MI355X.
// R8: R7 build chain kept (bucket partition + LDS-int adjw).
//   gemm: 4x4 register-blocked, X transposed in LDS -> 2x ds_read_b128 per
//         k-step instead of 17 scalar ds_read_b32 (was LDS-issue-bound at
//         31% VALUBusy / 9% of fp32 peak).
//   agg:  8 lanes x 16B per edge (uint4 = full 128B row across 8 lanes);
//         4x fewer gather instrs, 8x fewer shfl, register accumulation,
//         shfl_xor tree reduce over edge-slots.

#define FDIM 64
#define BKT 128              // nodes per bucket
#define MAXNB 1024           // max buckets supported (N <= 131072)

// ---------- build: bucket partition ----------

__global__ __launch_bounds__(256) void partA_kernel(const int* __restrict__ ecol,
                                                    int* __restrict__ gcnt,
                                                    int e, int nb, int epb) {
    __shared__ int lh[MAXNB];
    const int t = threadIdx.x;
    for (int i = t; i < nb; i += 256) lh[i] = 0;
    __syncthreads();
    int s = blockIdx.x * epb;
    int en = s + epb; if (en > e) en = e;
    for (int i = s + t; i < en; i += 256) atomicAdd(&lh[ecol[i] >> 7], 1);
    __syncthreads();
    for (int i = t; i < nb; i += 256)
        if (lh[i]) atomicAdd(&gcnt[i], lh[i]);
}

__global__ __launch_bounds__(1024) void scan_kernel(const int* __restrict__ gcnt,
                                                    int* __restrict__ base,
                                                    int* __restrict__ cursor, int nb) {
    __shared__ int s[1024];
    const int t = threadIdx.x;
    int v = (t < nb) ? gcnt[t] : 0;
    s[t] = v;
    __syncthreads();
    for (int off = 1; off < 1024; off <<= 1) {
        int x = (t >= off) ? s[t - off] : 0;
        __syncthreads();
        s[t] += x;
        __syncthreads();
    }
    int incl = s[t];
    if (t < nb) { base[t] = incl - v; cursor[t] = incl - v; }
    if (t == nb - 1) base[nb] = incl;
}

__global__ __launch_bounds__(256) void partB_kernel(const int* __restrict__ erow,
                                                    const int* __restrict__ ecol,
                                                    int* __restrict__ cursor,
                                                    unsigned* __restrict__ part,
                                                    int e, int nb, int epb) {
    __shared__ int lh[MAXNB];
    __shared__ int lbase[MAXNB];
    const int t = threadIdx.x;
    for (int i = t; i < nb; i += 256) lh[i] = 0;
    __syncthreads();
    int s = blockIdx.x * epb;
    int en = s + epb; if (en > e) en = e;
    for (int i = s + t; i < en; i += 256) atomicAdd(&lh[ecol[i] >> 7], 1);
    __syncthreads();
    for (int i = t; i < nb; i += 256)
        lbase[i] = lh[i] ? atomicAdd(&cursor[i], lh[i]) : 0;
    __syncthreads();
    for (int i = t; i < nb; i += 256) lh[i] = 0;
    __syncthreads();
    for (int i = s + t; i < en; i += 256) {
        int c = ecol[i];
        int b = c >> 7;
        int off = atomicAdd(&lh[b], 1);
        part[lbase[b] + off] = ((unsigned)erow[i] << 7) | (unsigned)(c & 127);
    }
}

// per-bucket: partitioned edges -> fixed-stride adjacency + per-node degree.
__global__ __launch_bounds__(256) void adjw_kernel(const unsigned* __restrict__ part,
                                                   const int* __restrict__ base,
                                                   int* __restrict__ cnt,
                                                   int* __restrict__ adjF,
                                                   int n, int cap) {
    const int b = blockIdx.x;
    const int v0 = b << 7;
    __shared__ int lc[BKT];
    const int t = threadIdx.x;
    if (t < BKT) lc[t] = 0;
    __syncthreads();
    const int s0 = base[b], s1 = base[b + 1];
    for (int e = s0 + t; e < s1; e += 256) {
        unsigned pk = part[e];
        int c = pk & 127;
        int slot = atomicAdd(&lc[c], 1);
        if (slot < cap) adjF[(size_t)(v0 + c) * cap + slot] = (int)(pk >> 7);
    }
    __syncthreads();
    int nn = n - v0; if (nn > BKT) nn = BKT;
    if (t < nn) cnt[v0 + t] = lc[t];
}

// ---------- per-layer compute ----------

// Hs[n,64] = bf16( rsqrt(cnt+1) * (X[n,64] @ W[64,64]) )
// 4x4 register-blocked: thread (tr,tc) computes rows 4tr..+3, cols 4tc..+3.
// XT[k][r] (transposed) and Ws[k][j] padded to 68 -> float4 LDS reads.
__global__ __launch_bounds__(256) void gemm_kernel(const float* __restrict__ X,
                                                   const float* __restrict__ W,
                                                   const int* __restrict__ cnt,
                                                   __hip_bfloat16* __restrict__ Hout, int n) {
    __shared__ float XT[64][68];
    __shared__ float Ws[64][68];
    const int t = threadIdx.x;
    const int row0 = blockIdx.x * 64;
    #pragma unroll
    for (int i = t; i < 4096; i += 256) Ws[i >> 6][i & 63] = W[i];
    #pragma unroll
    for (int i = t; i < 4096; i += 256) {
        int r = i >> 6, c = i & 63;
        int gr = row0 + r;
        XT[c][r] = (gr < n) ? X[(size_t)gr * FDIM + c] : 0.0f;   // coalesced read
    }
    __syncthreads();

    const int tc = t & 15;        // col block
    const int tr = t >> 4;        // row block
    float acc[4][4];
    #pragma unroll
    for (int i = 0; i < 4; i++)
        #pragma unroll
        for (int j = 0; j < 4; j++) acc[i][j] = 0.0f;

    #pragma unroll 8
    for (int k = 0; k < 64; k++) {
        float4 a = *(const float4*)&XT[k][4 * tr];
        float4 b = *(const float4*)&Ws[k][4 * tc];
        acc[0][0] += a.x * b.x; acc[0][1] += a.x * b.y; acc[0][2] += a.x * b.z; acc[0][3] += a.x * b.w;
        acc[1][0] += a.y * b.x; acc[1][1] += a.y * b.y; acc[1][2] += a.y * b.z; acc[1][3] += a.y * b.w;
        acc[2][0] += a.z * b.x; acc[2][1] += a.z * b.y; acc[2][2] += a.z * b.z; acc[2][3] += a.z * b.w;
        acc[3][0] += a.w * b.x; acc[3][1] += a.w * b.y; acc[3][2] += a.w * b.z; acc[3][3] += a.w * b.w;
    }

    #pragma unroll
    for (int i = 0; i < 4; i++) {
        int gr = row0 + 4 * tr + i;
        if (gr < n) {
            float dv = rsqrtf((float)cnt[gr] + 1.0f);   // +1 self loop
            union { ushort4 u; __hip_bfloat16 h[4]; } pk;
            pk.h[0] = __float2bfloat16(acc[i][0] * dv);
            pk.h[1] = __float2bfloat16(acc[i][1] * dv);
            pk.h[2] = __float2bfloat16(acc[i][2] * dv);
            pk.h[3] = __float2bfloat16(acc[i][3] * dv);
            *(ushort4*)&Hout[(size_t)gr * FDIM + 4 * tc] = pk.u;   // 8B coalesced
        }
    }
}

__device__ inline void unpack_add(uint4 w, float* a) {
    a[0] += __uint_as_float(w.x << 16);
    a[1] += __uint_as_float(w.x & 0xffff0000u);
    a[2] += __uint_as_float(w.y << 16);
    a[3] += __uint_as_float(w.y & 0xffff0000u);
    a[4] += __uint_as_float(w.z << 16);
    a[5] += __uint_as_float(w.z & 0xffff0000u);
    a[6] += __uint_as_float(w.w << 16);
    a[7] += __uint_as_float(w.w & 0xffff0000u);
}

// out[v][:] = dinv(v) * ( hs[v][:] + sum_{u in N_in(v)} hs[u][:] ) + b ; optional ELU.
// Wave per node. 8 lanes x 16B per edge: lane = (edge slot es = lane>>3,
// feature slice sl = lane&7 covering feats 8sl..8sl+7). Register accum,
// shfl_xor tree reduce over es.
__global__ __launch_bounds__(256) void agg_kernel(const __hip_bfloat16* __restrict__ hs,
                                                  const int* __restrict__ adjF,
                                                  const int* __restrict__ cnt,
                                                  const float* __restrict__ bias,
                                                  float* __restrict__ out,
                                                  int n, int cap, int do_elu,
                                                  const int* __restrict__ erow,
                                                  const int* __restrict__ ecol, int etot) {
    const int v = blockIdx.x * 4 + (threadIdx.x >> 6);
    const int lane = threadIdx.x & 63;
    if (v >= n) return;
    const int sl = lane & 7;       // feature slice (16B = 8 bf16)
    const int es = lane >> 3;      // edge slot 0..7
    const int deg = cnt[v];
    const float dv = rsqrtf((float)deg + 1.0f);         // +1 self loop
    const uint4* __restrict__ hs4 = (const uint4*)hs;

    float a[8];
    #pragma unroll
    for (int j = 0; j < 8; j++) a[j] = 0.0f;

    // self loop (once: es==0 group covers all 8 slices)
    if (es == 0) {
        uint4 w = hs4[(size_t)v * 8 + sl];
        unpack_add(w, a);
    }

    if (deg <= cap) {                       // fast path (always, in practice)
        const int* __restrict__ av = adjF + (size_t)v * cap;
        for (int base = 0; base < deg; base += 64) {
            int m = deg - base; if (m > 64) m = 64;
            int uvec = 0;
            if (lane < m) uvec = av[base + lane];        // coalesced
            int g = 0;
            for (; g + 16 <= m; g += 16) {               // 2 edges/lane-group per iter
                int u0 = __shfl(uvec, g + es, 64);
                int u1 = __shfl(uvec, g + 8 + es, 64);
                uint4 w0 = hs4[(size_t)u0 * 8 + sl];
                uint4 w1 = hs4[(size_t)u1 * 8 + sl];
                unpack_add(w0, a);
                unpack_add(w1, a);
            }
            for (; g < m; g += 8) {
                int idx = g + es;
                int u = __shfl(uvec, (idx < m) ? idx : 0, 64);
                if (idx < m) {
                    uint4 w = hs4[(size_t)u * 8 + sl];
                    unpack_add(w, a);
                }
            }
        }
    } else {
        // slow path: deg > cap (prob ~0) — wave-cooperative scan of raw edges
        for (int base = 0; base < etot; base += 64) {
            int m = etot - base; if (m > 64) m = 64;
            int c = -1, r = 0;
            if (lane < m) { c = ecol[base + lane]; r = erow[base + lane]; }
            unsigned long long mask = __ballot(c == v);
            while (mask) {
                int j = __ffsll((long long)mask) - 1;
                mask &= mask - 1;
                int u = __shfl(r, j, 64);
                if (es == 0) {
                    uint4 w = hs4[(size_t)u * 8 + sl];
                    unpack_add(w, a);
                }
            }
        }
    }

    // reduce across the 8 edge slots (lanes sl, sl+8, ..., sl+56)
    #pragma unroll
    for (int off = 8; off < 64; off <<= 1) {
        #pragma unroll
        for (int j = 0; j < 8; j++) a[j] += __shfl_xor(a[j], off, 64);
    }

    if (es == 0) {
        float4 r0, r1;
        r0.x = a[0] * dv + bias[8 * sl + 0];
        r0.y = a[1] * dv + bias[8 * sl + 1];
        r0.z = a[2] * dv + bias[8 * sl + 2];
        r0.w = a[3] * dv + bias[8 * sl + 3];
        r1.x = a[4] * dv + bias[8 * sl + 4];
        r1.y = a[5] * dv + bias[8 * sl + 5];
        r1.z = a[6] * dv + bias[8 * sl + 6];
        r1.w = a[7] * dv + bias[8 * sl + 7];
        if (do_elu) {
            r0.x = (r0.x > 0.0f) ? r0.x : (__expf(r0.x) - 1.0f);
            r0.y = (r0.y > 0.0f) ? r0.y : (__expf(r0.y) - 1.0f);
            r0.z = (r0.z > 0.0f) ? r0.z : (__expf(r0.z) - 1.0f);
            r0.w = (r0.w > 0.0f) ? r0.w : (__expf(r0.w) - 1.0f);
            r1.x = (r1.x > 0.0f) ? r1.x : (__expf(r1.x) - 1.0f);
            r1.y = (r1.y > 0.0f) ? r1.y : (__expf(r1.y) - 1.0f);
            r1.z = (r1.z > 0.0f) ? r1.z : (__expf(r1.z) - 1.0f);
            r1.w = (r1.w > 0.0f) ? r1.w : (__expf(r1.w) - 1.0f);
        }
        float4* op = (float4*)&out[(size_t)v * FDIM + 8 * sl];
        op[0] = r0;
        op[1] = r1;
    }
}

// ---------- launch ----------

extern "C" void kernel_launch(void* const* d_in, const int* in_sizes, int n_in,
                              void* d_out, int out_size, void* d_ws, size_t ws_size,
                              hipStream_t stream) {
    const float* x   = (const float*)d_in[0];
    const int*   ei  = (const int*)d_in[1];
    const float* W1  = (const float*)d_in[2];
    const float* b1  = (const float*)d_in[3];
    const float* W2  = (const float*)d_in[4];
    const float* b2  = (const float*)d_in[5];
    const float* W3  = (const float*)d_in[6];
    const float* b3  = (const float*)d_in[7];

    const int N = in_sizes[0] / FDIM;      // 100000
    const int E = in_sizes[1] / 2;         // 1600000
    const int* erow = ei;                   // sources
    const int* ecol = ei + E;               // targets

    const int NB = (N + BKT - 1) / BKT;    // 782 buckets

    char* p = (char*)d_ws;
    __hip_bfloat16* hsb = (__hip_bfloat16*)p;  p += (size_t)N * FDIM * sizeof(__hip_bfloat16); // 12.8 MB
    int*   cnt  = (int*)p;   p += (size_t)N * sizeof(int);
    int* gcnt   = (int*)p;   p += (size_t)(NB + 1) * sizeof(int);
    int* bbase  = (int*)p;   p += (size_t)(NB + 1) * sizeof(int);
    int* cursor = (int*)p;   p += (size_t)(NB + 1) * sizeof(int);
    int*   adjF = (int*)p;

    // part[] aliases hsb: E*4 = 6.4MB <= N*128B = 12.8MB; dead before gemm1 writes hsb.
    unsigned* part = (unsigned*)hsb;

    // adjacency capacity: biggest of {64,48,32} that fits the workspace
    size_t used = (size_t)(p - (char*)d_ws);
    int cap = 64;
    while (cap > 32 && used + (size_t)N * cap * sizeof(int) > ws_size) cap -= 16;

    float* outb = (float*)d_out;

    const int TB = 256;
    const int PBLK = 256;                        // partition blocks
    const int epb = (E + PBLK - 1) / PBLK;       // edges per partition block
    const int nblkG = (N + 63) / 64;
    const int nblkA = (N + 3) / 4;

    hipMemsetAsync(gcnt, 0, (size_t)(NB + 1) * sizeof(int), stream);
    partA_kernel<<<PBLK, TB, 0, stream>>>(ecol, gcnt, E, NB, epb);
    scan_kernel<<<1, 1024, 0, stream>>>(gcnt, bbase, cursor, NB);
    partB_kernel<<<PBLK, TB, 0, stream>>>(erow, ecol, cursor, part, E, NB, epb);
    adjw_kernel<<<NB, TB, 0, stream>>>(part, bbase, cnt, adjF, N, cap);

    gemm_kernel<<<nblkG, TB, 0, stream>>>(x, W1, cnt, hsb, N);
    agg_kernel<<<nblkA, TB, 0, stream>>>(hsb, adjF, cnt, b1, outb, N, cap, 1, erow, ecol, E);
    gemm_kernel<<<nblkG, TB, 0, stream>>>(outb, W2, cnt, hsb, N);
    agg_kernel<<<nblkA, TB, 0, stream>>>(hsb, adjF, cnt, b2, outb, N, cap, 1, erow, ecol, E);
    gemm_kernel<<<nblkG, TB, 0, stream>>>(outb, W3, cnt, hsb, N);
    agg_kernel<<<nblkA, TB, 0, stream>>>(hsb, adjF, cnt, b3, outb, N, cap, 0, erow, ecol, E);
}

// Round 6
// 352.619 us; speedup vs baseline: 6.5634x; 1.0103x over previous
//
#include <hip/hip_runtime.h>
#include <hip/hip_bf16.h>
#include <math.h>

// 3-layer GCN on MI355X.
// R9: partA/partB occupancy fix — 512 blocks x 1024 threads (was 256x256 =
//     1 blk/CU, 4 waves, 8.7% occupancy, latency-starved at 1.4% VALU).
//     agg: float2 ext-vector accumulators -> v_pk_add_f32/v_pk_mul_f32
//     (unpack cost 2.0 -> 1.5 VALU ops per feature; agg was 62% VALUBusy).

#define FDIM 64
#define BKT 128              // nodes per bucket
#define MAXNB 1024           // max buckets supported (N <= 131072)

typedef float f32x2 __attribute__((ext_vector_type(2)));

// ---------- build: bucket partition ----------

__global__ __launch_bounds__(1024) void partA_kernel(const int* __restrict__ ecol,
                                                     int* __restrict__ gcnt,
                                                     int e, int nb, int epb) {
    __shared__ int lh[MAXNB];
    const int t = threadIdx.x;
    for (int i = t; i < nb; i += 1024) lh[i] = 0;
    __syncthreads();
    int s = blockIdx.x * epb;
    int en = s + epb; if (en > e) en = e;
    for (int i = s + t; i < en; i += 1024) atomicAdd(&lh[ecol[i] >> 7], 1);
    __syncthreads();
    for (int i = t; i < nb; i += 1024)
        if (lh[i]) atomicAdd(&gcnt[i], lh[i]);
}

__global__ __launch_bounds__(1024) void scan_kernel(const int* __restrict__ gcnt,
                                                    int* __restrict__ base,
                                                    int* __restrict__ cursor, int nb) {
    __shared__ int s[1024];
    const int t = threadIdx.x;
    int v = (t < nb) ? gcnt[t] : 0;
    s[t] = v;
    __syncthreads();
    for (int off = 1; off < 1024; off <<= 1) {
        int x = (t >= off) ? s[t - off] : 0;
        __syncthreads();
        s[t] += x;
        __syncthreads();
    }
    int incl = s[t];
    if (t < nb) { base[t] = incl - v; cursor[t] = incl - v; }
    if (t == nb - 1) base[nb] = incl;
}

__global__ __launch_bounds__(1024) void partB_kernel(const int* __restrict__ erow,
                                                     const int* __restrict__ ecol,
                                                     int* __restrict__ cursor,
                                                     unsigned* __restrict__ part,
                                                     int e, int nb, int epb) {
    __shared__ int lh[MAXNB];
    __shared__ int lbase[MAXNB];
    const int t = threadIdx.x;
    for (int i = t; i < nb; i += 1024) lh[i] = 0;
    __syncthreads();
    int s = blockIdx.x * epb;
    int en = s + epb; if (en > e) en = e;
    for (int i = s + t; i < en; i += 1024) atomicAdd(&lh[ecol[i] >> 7], 1);
    __syncthreads();
    for (int i = t; i < nb; i += 1024)
        lbase[i] = lh[i] ? atomicAdd(&cursor[i], lh[i]) : 0;
    __syncthreads();
    for (int i = t; i < nb; i += 1024) lh[i] = 0;
    __syncthreads();
    for (int i = s + t; i < en; i += 1024) {
        int c = ecol[i];
        int b = c >> 7;
        int off = atomicAdd(&lh[b], 1);
        part[lbase[b] + off] = ((unsigned)erow[i] << 7) | (unsigned)(c & 127);
    }
}

// per-bucket: partitioned edges -> fixed-stride adjacency + per-node degree.
__global__ __launch_bounds__(256) void adjw_kernel(const unsigned* __restrict__ part,
                                                   const int* __restrict__ base,
                                                   int* __restrict__ cnt,
                                                   int* __restrict__ adjF,
                                                   int n, int cap) {
    const int b = blockIdx.x;
    const int v0 = b << 7;
    __shared__ int lc[BKT];
    const int t = threadIdx.x;
    if (t < BKT) lc[t] = 0;
    __syncthreads();
    const int s0 = base[b], s1 = base[b + 1];
    for (int e = s0 + t; e < s1; e += 256) {
        unsigned pk = part[e];
        int c = pk & 127;
        int slot = atomicAdd(&lc[c], 1);
        if (slot < cap) adjF[(size_t)(v0 + c) * cap + slot] = (int)(pk >> 7);
    }
    __syncthreads();
    int nn = n - v0; if (nn > BKT) nn = BKT;
    if (t < nn) cnt[v0 + t] = lc[t];
}

// ---------- per-layer compute ----------

// Hs[n,64] = bf16( rsqrt(cnt+1) * (X[n,64] @ W[64,64]) )
// 4x4 register-blocked: thread (tr,tc) computes rows 4tr..+3, cols 4tc..+3.
__global__ __launch_bounds__(256) void gemm_kernel(const float* __restrict__ X,
                                                   const float* __restrict__ W,
                                                   const int* __restrict__ cnt,
                                                   __hip_bfloat16* __restrict__ Hout, int n) {
    __shared__ float XT[64][68];
    __shared__ float Ws[64][68];
    const int t = threadIdx.x;
    const int row0 = blockIdx.x * 64;
    #pragma unroll
    for (int i = t; i < 4096; i += 256) Ws[i >> 6][i & 63] = W[i];
    #pragma unroll
    for (int i = t; i < 4096; i += 256) {
        int r = i >> 6, c = i & 63;
        int gr = row0 + r;
        XT[c][r] = (gr < n) ? X[(size_t)gr * FDIM + c] : 0.0f;   // coalesced read
    }
    __syncthreads();

    const int tc = t & 15;        // col block
    const int tr = t >> 4;        // row block
    float acc[4][4];
    #pragma unroll
    for (int i = 0; i < 4; i++)
        #pragma unroll
        for (int j = 0; j < 4; j++) acc[i][j] = 0.0f;

    #pragma unroll 8
    for (int k = 0; k < 64; k++) {
        float4 a = *(const float4*)&XT[k][4 * tr];
        float4 b = *(const float4*)&Ws[k][4 * tc];
        acc[0][0] += a.x * b.x; acc[0][1] += a.x * b.y; acc[0][2] += a.x * b.z; acc[0][3] += a.x * b.w;
        acc[1][0] += a.y * b.x; acc[1][1] += a.y * b.y; acc[1][2] += a.y * b.z; acc[1][3] += a.y * b.w;
        acc[2][0] += a.z * b.x; acc[2][1] += a.z * b.y; acc[2][2] += a.z * b.z; acc[2][3] += a.z * b.w;
        acc[3][0] += a.w * b.x; acc[3][1] += a.w * b.y; acc[3][2] += a.w * b.z; acc[3][3] += a.w * b.w;
    }

    #pragma unroll
    for (int i = 0; i < 4; i++) {
        int gr = row0 + 4 * tr + i;
        if (gr < n) {
            float dv = rsqrtf((float)cnt[gr] + 1.0f);   // +1 self loop
            union { ushort4 u; __hip_bfloat16 h[4]; } pk;
            pk.h[0] = __float2bfloat16(acc[i][0] * dv);
            pk.h[1] = __float2bfloat16(acc[i][1] * dv);
            pk.h[2] = __float2bfloat16(acc[i][2] * dv);
            pk.h[3] = __float2bfloat16(acc[i][3] * dv);
            *(ushort4*)&Hout[(size_t)gr * FDIM + 4 * tc] = pk.u;   // 8B coalesced
        }
    }
}

__device__ inline f32x2 bf2f(unsigned u) {
    f32x2 r;
    r.x = __uint_as_float(u << 16);
    r.y = __uint_as_float(u & 0xffff0000u);
    return r;
}

__device__ inline void unpack_add(uint4 w, f32x2* a) {
    a[0] += bf2f(w.x);      // v_pk_add_f32
    a[1] += bf2f(w.y);
    a[2] += bf2f(w.z);
    a[3] += bf2f(w.w);
}

// out[v][:] = dinv(v) * ( hs[v][:] + sum_{u in N_in(v)} hs[u][:] ) + b ; optional ELU.
// Wave per node. 8 lanes x 16B per edge: es = lane>>3 edge slot, sl = lane&7
// feature slice (8 feats). Packed f32x2 accumulation, shfl_xor tree reduce.
__global__ __launch_bounds__(256) void agg_kernel(const __hip_bfloat16* __restrict__ hs,
                                                  const int* __restrict__ adjF,
                                                  const int* __restrict__ cnt,
                                                  const float* __restrict__ bias,
                                                  float* __restrict__ out,
                                                  int n, int cap, int do_elu,
                                                  const int* __restrict__ erow,
                                                  const int* __restrict__ ecol, int etot) {
    const int v = blockIdx.x * 4 + (threadIdx.x >> 6);
    const int lane = threadIdx.x & 63;
    if (v >= n) return;
    const int sl = lane & 7;       // feature slice (16B = 8 bf16)
    const int es = lane >> 3;      // edge slot 0..7
    const int deg = cnt[v];
    const float dv = rsqrtf((float)deg + 1.0f);         // +1 self loop
    const uint4* __restrict__ hs4 = (const uint4*)hs;

    f32x2 a[4];
    #pragma unroll
    for (int j = 0; j < 4; j++) a[j] = (f32x2)(0.0f);

    // self loop (once: es==0 group covers all 8 slices)
    if (es == 0) {
        uint4 w = hs4[(size_t)v * 8 + sl];
        unpack_add(w, a);
    }

    if (deg <= cap) {                       // fast path (always, in practice)
        const int* __restrict__ av = adjF + (size_t)v * cap;
        for (int base = 0; base < deg; base += 64) {
            int m = deg - base; if (m > 64) m = 64;
            int uvec = 0;
            if (lane < m) uvec = av[base + lane];        // coalesced
            int g = 0;
            for (; g + 16 <= m; g += 16) {               // 2 edges/lane-group per iter
                int u0 = __shfl(uvec, g + es, 64);
                int u1 = __shfl(uvec, g + 8 + es, 64);
                uint4 w0 = hs4[(size_t)u0 * 8 + sl];
                uint4 w1 = hs4[(size_t)u1 * 8 + sl];
                unpack_add(w0, a);
                unpack_add(w1, a);
            }
            for (; g < m; g += 8) {
                int idx = g + es;
                int u = __shfl(uvec, (idx < m) ? idx : 0, 64);
                if (idx < m) {
                    uint4 w = hs4[(size_t)u * 8 + sl];
                    unpack_add(w, a);
                }
            }
        }
    } else {
        // slow path: deg > cap (prob ~0) — wave-cooperative scan of raw edges
        for (int base = 0; base < etot; base += 64) {
            int m = etot - base; if (m > 64) m = 64;
            int c = -1, r = 0;
            if (lane < m) { c = ecol[base + lane]; r = erow[base + lane]; }
            unsigned long long mask = __ballot(c == v);
            while (mask) {
                int j = __ffsll((long long)mask) - 1;
                mask &= mask - 1;
                int u = __shfl(r, j, 64);
                if (es == 0) {
                    uint4 w = hs4[(size_t)u * 8 + sl];
                    unpack_add(w, a);
                }
            }
        }
    }

    // reduce across the 8 edge slots (lanes sl, sl+8, ..., sl+56)
    #pragma unroll
    for (int off = 8; off < 64; off <<= 1) {
        #pragma unroll
        for (int j = 0; j < 4; j++) {
            f32x2 o;
            o.x = __shfl_xor(a[j].x, off, 64);
            o.y = __shfl_xor(a[j].y, off, 64);
            a[j] += o;                                   // v_pk_add_f32
        }
    }

    if (es == 0) {
        const f32x2* b2 = (const f32x2*)&bias[8 * sl];
        float r[8];
        #pragma unroll
        for (int j = 0; j < 4; j++) {
            f32x2 t = a[j] * dv + b2[j];                 // v_pk_fma-ish
            r[2 * j] = t.x;
            r[2 * j + 1] = t.y;
        }
        if (do_elu) {
            #pragma unroll
            for (int j = 0; j < 8; j++)
                r[j] = (r[j] > 0.0f) ? r[j] : (__expf(r[j]) - 1.0f);
        }
        float4* op = (float4*)&out[(size_t)v * FDIM + 8 * sl];
        op[0] = make_float4(r[0], r[1], r[2], r[3]);
        op[1] = make_float4(r[4], r[5], r[6], r[7]);
    }
}

// ---------- launch ----------

extern "C" void kernel_launch(void* const* d_in, const int* in_sizes, int n_in,
                              void* d_out, int out_size, void* d_ws, size_t ws_size,
                              hipStream_t stream) {
    const float* x   = (const float*)d_in[0];
    const int*   ei  = (const int*)d_in[1];
    const float* W1  = (const float*)d_in[2];
    const float* b1  = (const float*)d_in[3];
    const float* W2  = (const float*)d_in[4];
    const float* b2  = (const float*)d_in[5];
    const float* W3  = (const float*)d_in[6];
    const float* b3  = (const float*)d_in[7];

    const int N = in_sizes[0] / FDIM;      // 100000
    const int E = in_sizes[1] / 2;         // 1600000
    const int* erow = ei;                   // sources
    const int* ecol = ei + E;               // targets

    const int NB = (N + BKT - 1) / BKT;    // 782 buckets

    char* p = (char*)d_ws;
    __hip_bfloat16* hsb = (__hip_bfloat16*)p;  p += (size_t)N * FDIM * sizeof(__hip_bfloat16); // 12.8 MB
    int*   cnt  = (int*)p;   p += (size_t)N * sizeof(int);
    int* gcnt   = (int*)p;   p += (size_t)(NB + 1) * sizeof(int);
    int* bbase  = (int*)p;   p += (size_t)(NB + 1) * sizeof(int);
    int* cursor = (int*)p;   p += (size_t)(NB + 1) * sizeof(int);
    int*   adjF = (int*)p;

    // part[] aliases hsb: E*4 = 6.4MB <= N*128B = 12.8MB; dead before gemm1 writes hsb.
    unsigned* part = (unsigned*)hsb;

    // adjacency capacity: biggest of {64,48,32} that fits the workspace
    size_t used = (size_t)(p - (char*)d_ws);
    int cap = 64;
    while (cap > 32 && used + (size_t)N * cap * sizeof(int) > ws_size) cap -= 16;

    float* outb = (float*)d_out;

    const int TB = 256;
    const int PBLK = 512;                        // partition blocks (1024 thr each)
    const int epb = (E + PBLK - 1) / PBLK;       // edges per partition block
    const int nblkG = (N + 63) / 64;
    const int nblkA = (N + 3) / 4;

    hipMemsetAsync(gcnt, 0, (size_t)(NB + 1) * sizeof(int), stream);
    partA_kernel<<<PBLK, 1024, 0, stream>>>(ecol, gcnt, E, NB, epb);
    scan_kernel<<<1, 1024, 0, stream>>>(gcnt, bbase, cursor, NB);
    partB_kernel<<<PBLK, 1024, 0, stream>>>(erow, ecol, cursor, part, E, NB, epb);
    adjw_kernel<<<NB, TB, 0, stream>>>(part, bbase, cnt, adjF, N, cap);

    gemm_kernel<<<nblkG, TB, 0, stream>>>(x, W1, cnt, hsb, N);
    agg_kernel<<<nblkA, TB, 0, stream>>>(hsb, adjF, cnt, b1, outb, N, cap, 1, erow, ecol, E);
    gemm_kernel<<<nblkG, TB, 0, stream>>>(outb, W2, cnt, hsb, N);
    agg_kernel<<<nblkA, TB, 0, stream>>>(hsb, adjF, cnt, b2, outb, N, cap, 1, erow, ecol, E);
    gemm_kernel<<<nblkG, TB, 0, stream>>>(outb, W3, cnt, hsb, N);
    agg_kernel<<<nblkA, TB, 0, stream>>>(hsb, adjF, cnt, b3, outb, N, cap, 0, erow, ecol, E);
}